// Round 1
// baseline (294.883 us; speedup 1.0000x reference)
//
#include <hip/hip_runtime.h>
#include <hip/hip_bf16.h>
#include <cmath>

typedef float f32x4 __attribute__((ext_vector_type(4)));
typedef __bf16 bf16x8 __attribute__((ext_vector_type(8)));

#define NE 8
#define H 1024
#define DF 2048
#define WCOLS 16384
#define NTOK 4096
#define MROWS 8192
#define NBLK 64
#define BK 32
#define LDA 40   // padded LDS stride in bf16 elems (80 B = 20 banks -> 2-way max)

// ---------------- Router: logits + top-2 + normalized weights ----------------
__global__ __launch_bounds__(256) void router_kernel(
    const float* __restrict__ x, const float* __restrict__ rw,
    float* __restrict__ logits, int* __restrict__ sel, float* __restrict__ rwn)
{
    int gid  = blockIdx.x * blockDim.x + threadIdx.x;
    int tok  = gid >> 6;
    int lane = gid & 63;
    const float* xr = x + (size_t)tok * H;
    float acc[NE];
#pragma unroll
    for (int e = 0; e < NE; ++e) acc[e] = 0.f;
#pragma unroll
    for (int it = 0; it < 4; ++it) {
        int k = (it * 64 + lane) * 4;
        float4 xv = *(const float4*)(xr + k);
#pragma unroll
        for (int e = 0; e < NE; ++e) {
            float4 wv = *(const float4*)(rw + e * H + k);
            acc[e] += xv.x * wv.x + xv.y * wv.y + xv.z * wv.z + xv.w * wv.w;
        }
    }
#pragma unroll
    for (int e = 0; e < NE; ++e) {
        float v = acc[e];
#pragma unroll
        for (int off = 32; off > 0; off >>= 1) v += __shfl_xor(v, off, 64);
        acc[e] = v;
    }
    if (lane == 0) {
#pragma unroll
        for (int e = 0; e < NE; ++e) logits[tok * NE + e] = acc[e];
        // top-2 on logits (softmax monotone); strict > keeps smallest index on tie
        int i1 = 0; float m1 = acc[0];
#pragma unroll
        for (int e = 1; e < NE; ++e) if (acc[e] > m1) { m1 = acc[e]; i1 = e; }
        int i2 = -1; float m2 = -INFINITY;
#pragma unroll
        for (int e = 0; e < NE; ++e) if (e != i1 && acc[e] > m2) { m2 = acc[e]; i2 = e; }
        float e2 = expf(m2 - m1);
        float inv = 1.f / (1.f + e2);
        sel[tok * 2]     = i1;  sel[tok * 2 + 1] = i2;
        rwn[tok * 2]     = inv; rwn[tok * 2 + 1] = e2 * inv;
    }
}

// ---------------- Stable counting sort by expert (1 block) ----------------
__global__ __launch_bounds__(256) void sort_kernel(
    const int* __restrict__ sel, const float* __restrict__ rwn,
    int* __restrict__ stok, float* __restrict__ srw, int* __restrict__ bexp)
{
    __shared__ int cnt[NE][256];
    __shared__ int tot[NE];
    __shared__ int ebase[NE + 1];
    int t = threadIdx.x;
    int selv[32];
    int lc[NE];
#pragma unroll
    for (int e = 0; e < NE; ++e) lc[e] = 0;
    int base = t * 32;
    for (int j = 0; j < 32; ++j) { selv[j] = sel[base + j]; lc[selv[j]]++; }
#pragma unroll
    for (int e = 0; e < NE; ++e) cnt[e][t] = lc[e];
    __syncthreads();
    if (t < NE) {                      // exclusive scan per expert over threads
        int s = 0;
        for (int i = 0; i < 256; ++i) { int c = cnt[t][i]; cnt[t][i] = s; s += c; }
        tot[t] = s;
    }
    __syncthreads();
    if (t == 0) {                      // expert bases
        int s = 0;
        for (int e = 0; e < NE; ++e) { ebase[e] = s; s += tot[e]; }
        ebase[NE] = s;                 // == 8192
    }
    __syncthreads();
    int off[NE];
#pragma unroll
    for (int e = 0; e < NE; ++e) off[e] = ebase[e] + cnt[e][t];
    for (int j = 0; j < 32; ++j) {
        int i = base + j;
        int e = selv[j];
        int pos = off[e]++;
        stok[pos] = i >> 1;            // source token = i / TOP_K
        srw[pos]  = rwn[i];
    }
    __syncthreads();
    if (t < NBLK) {                    // expert of first row of each 128-block
        int r = t * 128;
        int e = 0;
        while (e < NE - 1 && r >= ebase[e + 1]) ++e;
        bexp[t] = e;
    }
}

// ---------------- Block GEMM + GeLU * rw ----------------
__global__ __launch_bounds__(256) void moe_gemm(
    const float* __restrict__ x, const float* __restrict__ w1,
    const int* __restrict__ stok, const float* __restrict__ srw,
    const int* __restrict__ bexp, float* __restrict__ out)
{
    __shared__ __align__(16) __bf16 As[128 * LDA];   // A[m][k]
    __shared__ __align__(16) __bf16 Bs[128 * LDA];   // B^T: [n][k]
    __shared__ int   tokS[128];
    __shared__ float rwS[128];

    int bx = blockIdx.x;               // n-tile 0..15
    int by = blockIdx.y;               // m-block 0..63
    int tid = threadIdx.x;
    int e = bexp[by];
    const float* wbase = w1 + (size_t)e * DF + (size_t)bx * 128;

    if (tid < 128) {
        tokS[tid] = stok[by * 128 + tid];
        rwS[tid]  = srw[by * 128 + tid];
    }
    __syncthreads();

    int lane = tid & 63;
    int wv   = tid >> 6;               // 0..3
    int wm   = (wv & 1) * 64;
    int wn   = (wv >> 1) * 64;
    int quad = lane >> 4;              // 0..3
    int l16  = lane & 15;

    f32x4 acc[4][4];
#pragma unroll
    for (int i = 0; i < 4; ++i)
#pragma unroll
        for (int j = 0; j < 4; ++j) acc[i][j] = (f32x4){0.f, 0.f, 0.f, 0.f};

    for (int k0 = 0; k0 < H; k0 += BK) {
        // ---- stage A: 128 rows x 32 k, gathered, fp32->bf16 ----
        {
            int row = tid >> 1;
            int kh  = (tid & 1) * 16;
            const float* src = x + (size_t)tokS[row] * H + k0 + kh;
            float4 v0 = *(const float4*)(src);
            float4 v1 = *(const float4*)(src + 4);
            float4 v2 = *(const float4*)(src + 8);
            float4 v3 = *(const float4*)(src + 12);
            bf16x8 p0, p1;
            p0[0]=(__bf16)v0.x; p0[1]=(__bf16)v0.y; p0[2]=(__bf16)v0.z; p0[3]=(__bf16)v0.w;
            p0[4]=(__bf16)v1.x; p0[5]=(__bf16)v1.y; p0[6]=(__bf16)v1.z; p0[7]=(__bf16)v1.w;
            p1[0]=(__bf16)v2.x; p1[1]=(__bf16)v2.y; p1[2]=(__bf16)v2.z; p1[3]=(__bf16)v2.w;
            p1[4]=(__bf16)v3.x; p1[5]=(__bf16)v3.y; p1[6]=(__bf16)v3.z; p1[7]=(__bf16)v3.w;
            *(bf16x8*)&As[row * LDA + kh]     = p0;
            *(bf16x8*)&As[row * LDA + kh + 8] = p1;
        }
        // ---- stage B: 32 k x 128 n, transposed into [n][k], fp32->bf16 ----
#pragma unroll
        for (int it = 0; it < 4; ++it) {
            int idx = tid + it * 256;          // 0..1023
            int k  = idx >> 5;                 // 0..31
            int ng = idx & 31;                 // n group of 4
            float4 v = *(const float4*)(wbase + (size_t)(k0 + k) * WCOLS + ng * 4);
            Bs[(ng * 4 + 0) * LDA + k] = (__bf16)v.x;
            Bs[(ng * 4 + 1) * LDA + k] = (__bf16)v.y;
            Bs[(ng * 4 + 2) * LDA + k] = (__bf16)v.z;
            Bs[(ng * 4 + 3) * LDA + k] = (__bf16)v.w;
        }
        __syncthreads();
        // ---- fragments + MFMA ----
        bf16x8 af[4], bfr[4];
        int kf = quad * 8;
#pragma unroll
        for (int i = 0; i < 4; ++i)
            af[i] = *(const bf16x8*)&As[(wm + i * 16 + l16) * LDA + kf];
#pragma unroll
        for (int j = 0; j < 4; ++j)
            bfr[j] = *(const bf16x8*)&Bs[(wn + j * 16 + l16) * LDA + kf];
#pragma unroll
        for (int i = 0; i < 4; ++i)
#pragma unroll
            for (int j = 0; j < 4; ++j)
                acc[i][j] = __builtin_amdgcn_mfma_f32_16x16x32_bf16(
                    af[i], bfr[j], acc[i][j], 0, 0, 0);
        __syncthreads();
    }

    // ---- epilogue: gelu(exact) * rw, store ----
#pragma unroll
    for (int i = 0; i < 4; ++i) {
#pragma unroll
        for (int r = 0; r < 4; ++r) {
            int m = wm + i * 16 + quad * 4 + r;
            float rwv = rwS[m];
            size_t orow = (size_t)(by * 128 + m) * DF + bx * 128;
#pragma unroll
            for (int j = 0; j < 4; ++j) {
                float val = acc[i][j][r];
                float g = 0.5f * val * (1.f + erff(val * 0.70710678118654752f));
                out[orow + wn + j * 16 + l16] = g * rwv;
            }
        }
    }
}

extern "C" void kernel_launch(void* const* d_in, const int* in_sizes, int n_in,
                              void* d_out, int out_size, void* d_ws, size_t ws_size,
                              hipStream_t stream) {
    (void)in_sizes; (void)n_in; (void)out_size; (void)ws_size;
    const float* x        = (const float*)d_in[0];
    const float* router_w = (const float*)d_in[1];
    const float* w1       = (const float*)d_in[2];
    float* out    = (float*)d_out;
    float* logits = out + (size_t)MROWS * DF;   // output 1 follows output 0

    char* ws   = (char*)d_ws;
    int*   sel  = (int*)(ws);                  // 8192 ints
    float* rwn  = (float*)(ws + 32768);        // 8192 floats
    int*   stok = (int*)(ws + 65536);          // 8192 ints
    float* srw  = (float*)(ws + 98304);        // 8192 floats
    int*   bexp = (int*)(ws + 131072);         // 64 ints

    router_kernel<<<NTOK / 4, 256, 0, stream>>>(x, router_w, logits, sel, rwn);
    sort_kernel<<<1, 256, 0, stream>>>(sel, rwn, stok, srw, bexp);
    moe_gemm<<<dim3(16, NBLK), 256, 0, stream>>>(x, w1, stok, srw, bexp, out);
}

// Round 2
// 215.115 us; speedup vs baseline: 1.3708x; 1.3708x over previous
//
#include <hip/hip_runtime.h>
#include <hip/hip_bf16.h>
#include <cmath>

typedef float f32x4 __attribute__((ext_vector_type(4)));
typedef __bf16 bf16x8 __attribute__((ext_vector_type(8)));
typedef __bf16 bf16x4 __attribute__((ext_vector_type(4)));

#define NE 8
#define H 1024
#define DF 2048
#define WCOLS 16384
#define NTOK 4096
#define MROWS 8192
#define NBLK 64

typedef const __attribute__((address_space(1))) unsigned int glb_u32;
typedef __attribute__((address_space(3))) unsigned int lds_u32;

__device__ __forceinline__ void async_load16(const void* g, void* l) {
    __builtin_amdgcn_global_load_lds((glb_u32*)g, (lds_u32*)l, 16, 0, 0);
}

// ------------- Router: logits + top-2 weights + x -> bf16 -------------------
__global__ __launch_bounds__(256) void router_kernel(
    const float* __restrict__ x, const float* __restrict__ rw,
    float* __restrict__ logits, int* __restrict__ sel, float* __restrict__ rwn,
    __bf16* __restrict__ xb)
{
    int gid  = blockIdx.x * blockDim.x + threadIdx.x;
    int tok  = gid >> 6;
    int lane = gid & 63;
    const float* xr = x + (size_t)tok * H;
    __bf16* xbr = xb + (size_t)tok * H;
    float acc[NE];
#pragma unroll
    for (int e = 0; e < NE; ++e) acc[e] = 0.f;
#pragma unroll
    for (int it = 0; it < 4; ++it) {
        int k = (it * 64 + lane) * 4;
        float4 xv = *(const float4*)(xr + k);
        bf16x4 xc;
        xc[0] = (__bf16)xv.x; xc[1] = (__bf16)xv.y;
        xc[2] = (__bf16)xv.z; xc[3] = (__bf16)xv.w;
        *(bf16x4*)(xbr + k) = xc;
#pragma unroll
        for (int e = 0; e < NE; ++e) {
            float4 wv = *(const float4*)(rw + e * H + k);
            acc[e] += xv.x * wv.x + xv.y * wv.y + xv.z * wv.z + xv.w * wv.w;
        }
    }
#pragma unroll
    for (int e = 0; e < NE; ++e) {
        float v = acc[e];
#pragma unroll
        for (int off = 32; off > 0; off >>= 1) v += __shfl_xor(v, off, 64);
        acc[e] = v;
    }
    if (lane == 0) {
#pragma unroll
        for (int e = 0; e < NE; ++e) logits[tok * NE + e] = acc[e];
        int i1 = 0; float m1 = acc[0];
#pragma unroll
        for (int e = 1; e < NE; ++e) if (acc[e] > m1) { m1 = acc[e]; i1 = e; }
        int i2 = -1; float m2 = -INFINITY;
#pragma unroll
        for (int e = 0; e < NE; ++e) if (e != i1 && acc[e] > m2) { m2 = acc[e]; i2 = e; }
        float e2 = expf(m2 - m1);
        float inv = 1.f / (1.f + e2);
        sel[tok * 2]     = i1;  sel[tok * 2 + 1] = i2;
        rwn[tok * 2]     = inv; rwn[tok * 2 + 1] = e2 * inv;
    }
}

// ------------- w1 transpose+convert: [1024][16384] f32 -> [16384][1024] bf16 -
__global__ __launch_bounds__(256) void transpose_w(
    const float* __restrict__ w1, __bf16* __restrict__ w1t)
{
    __shared__ float tile[64][65];
    int kb = blockIdx.x * 64;
    int nb = blockIdx.y * 64;
    int t  = threadIdx.x;
    int kk = t >> 4;
    int nn = (t & 15) * 4;
#pragma unroll
    for (int r = 0; r < 4; ++r) {
        int k = kk + r * 16;
        float4 v = *(const float4*)(w1 + (size_t)(kb + k) * WCOLS + nb + nn);
        tile[k][nn]     = v.x;
        tile[k][nn + 1] = v.y;
        tile[k][nn + 2] = v.z;
        tile[k][nn + 3] = v.w;
    }
    __syncthreads();
    int n_local = t >> 2;
    int kc = (t & 3) * 16;
    bf16x8 o0, o1;
#pragma unroll
    for (int i = 0; i < 8; ++i) {
        o0[i] = (__bf16)tile[kc + i][n_local];
        o1[i] = (__bf16)tile[kc + 8 + i][n_local];
    }
    __bf16* dst = w1t + (size_t)(nb + n_local) * H + kb + kc;
    *(bf16x8*)dst       = o0;
    *(bf16x8*)(dst + 8) = o1;
}

// ------------- Stable counting sort by expert (1 block, parallel scan) -------
__global__ __launch_bounds__(256) void sort_kernel(
    const int* __restrict__ sel, const float* __restrict__ rwn,
    int* __restrict__ stok, float* __restrict__ srw, int* __restrict__ bexp)
{
    __shared__ int cnt[NE][256];
    __shared__ int tot[NE];
    __shared__ int ebase[NE + 1];
    int t = threadIdx.x;
    int selv[32];
    int lc[NE];
#pragma unroll
    for (int e = 0; e < NE; ++e) lc[e] = 0;
    int base = t * 32;
    for (int j = 0; j < 32; ++j) { selv[j] = sel[base + j]; lc[selv[j]]++; }
#pragma unroll
    for (int e = 0; e < NE; ++e) cnt[e][t] = lc[e];
    __syncthreads();
    // parallel exclusive scan: expert g handled by 32 threads (j = t&31)
    {
        int g = t >> 5, j = t & 31;
        int s = 0, pre[8];
#pragma unroll
        for (int i = 0; i < 8; ++i) { pre[i] = s; s += cnt[g][j * 8 + i]; }
        int inc = s;
#pragma unroll
        for (int d = 1; d < 32; d <<= 1) {
            int v = __shfl_up(inc, d, 64);
            if (j >= d) inc += v;
        }
        int excl = inc - s;
#pragma unroll
        for (int i = 0; i < 8; ++i) cnt[g][j * 8 + i] = excl + pre[i];
        if (j == 31) tot[g] = inc;
    }
    __syncthreads();
    if (t == 0) {
        int s = 0;
        for (int e = 0; e < NE; ++e) { ebase[e] = s; s += tot[e]; }
        ebase[NE] = s;
    }
    __syncthreads();
    int off[NE];
#pragma unroll
    for (int e = 0; e < NE; ++e) off[e] = ebase[e] + cnt[e][t];
    for (int j = 0; j < 32; ++j) {
        int i = base + j;
        int e = selv[j];
        int pos = off[e]++;
        stok[pos] = i >> 1;
        srw[pos]  = rwn[i];
    }
    __syncthreads();
    if (t < NBLK) {
        int r = t * 128;
        int e = 0;
        while (e < NE - 1 && r >= ebase[e + 1]) ++e;
        bexp[t] = e;
    }
}

// ------------- Block GEMM (m97 structure) + GeLU * rw ------------------------
__global__ __launch_bounds__(256) void moe_gemm(
    const __bf16* __restrict__ xb, const __bf16* __restrict__ w1t,
    const int* __restrict__ stok, const float* __restrict__ srw,
    const int* __restrict__ bexp, float* __restrict__ out)
{
    __shared__ __align__(16) __bf16 As[128 * 32];   // [m][k], unpadded (global_load_lds layout)
    __shared__ __align__(16) __bf16 Bs[128 * 32];   // [n][k]
    __shared__ int   tokS[128];
    __shared__ float rwS[128];

    int bx = blockIdx.x;               // n-tile 0..15
    int by = blockIdx.y;               // m-block 0..63
    int tid = threadIdx.x;
    int e = bexp[by];

    if (tid < 128) {
        tokS[tid] = stok[by * 128 + tid];
        rwS[tid]  = srw[by * 128 + tid];
    }
    __syncthreads();

    int lane = tid & 63;
    int wv   = tid >> 6;               // 0..3
    // staging: wave wv covers rows [wv*32, wv*32+32); lane -> (row, kchunk)
    int rsub = lane >> 2;              // 0..15
    int kc   = (lane & 3) * 8;         // elem offset within 32-k tile
    int r0   = wv * 32 + rsub;
    int r1   = r0 + 16;

    const char* aP0 = (const char*)(xb + (size_t)tokS[r0] * H + kc);
    const char* aP1 = (const char*)(xb + (size_t)tokS[r1] * H + kc);
    const __bf16* wbase = w1t + ((size_t)e * DF + (size_t)bx * 128) * H;
    const char* bP0 = (const char*)(wbase + (size_t)r0 * H + kc);
    const char* bP1 = (const char*)(wbase + (size_t)r1 * H + kc);
    __bf16* lA = As + wv * 1024;       // wave's LDS chunk (32 rows x 32 k)
    __bf16* lB = Bs + wv * 1024;

    int wm   = (wv & 1) * 64;
    int wn   = (wv >> 1) * 64;
    int quad = lane >> 4;
    int l16  = lane & 15;
    int kf   = quad * 8;

    f32x4 acc[4][4];
#pragma unroll
    for (int i = 0; i < 4; ++i)
#pragma unroll
        for (int j = 0; j < 4; ++j) acc[i][j] = (f32x4){0.f, 0.f, 0.f, 0.f};

    for (int k0 = 0; k0 < H; k0 += 32) {
        async_load16(aP0, lA);
        async_load16(aP1, lA + 512);
        async_load16(bP0, lB);
        async_load16(bP1, lB + 512);
        aP0 += 64; aP1 += 64; bP0 += 64; bP1 += 64;
        __syncthreads();               // drains vmcnt -> tiles visible

        bf16x8 af[4], bfr[4];
#pragma unroll
        for (int i = 0; i < 4; ++i)
            af[i] = *(const bf16x8*)&As[(wm + i * 16 + l16) * 32 + kf];
#pragma unroll
        for (int j = 0; j < 4; ++j)
            bfr[j] = *(const bf16x8*)&Bs[(wn + j * 16 + l16) * 32 + kf];
#pragma unroll
        for (int i = 0; i < 4; ++i)
#pragma unroll
            for (int j = 0; j < 4; ++j)
                acc[i][j] = __builtin_amdgcn_mfma_f32_16x16x32_bf16(
                    af[i], bfr[j], acc[i][j], 0, 0, 0);
        __syncthreads();               // all waves done reading before restage
    }

#pragma unroll
    for (int i = 0; i < 4; ++i) {
#pragma unroll
        for (int r = 0; r < 4; ++r) {
            int m = wm + i * 16 + quad * 4 + r;
            float rwv = rwS[m];
            size_t orow = (size_t)(by * 128 + m) * DF + bx * 128;
#pragma unroll
            for (int j = 0; j < 4; ++j) {
                float val = acc[i][j][r];
                float g = 0.5f * val * (1.f + erff(val * 0.70710678118654752f));
                out[orow + wn + j * 16 + l16] = g * rwv;
            }
        }
    }
}

extern "C" void kernel_launch(void* const* d_in, const int* in_sizes, int n_in,
                              void* d_out, int out_size, void* d_ws, size_t ws_size,
                              hipStream_t stream) {
    (void)in_sizes; (void)n_in; (void)out_size; (void)ws_size;
    const float* x        = (const float*)d_in[0];
    const float* router_w = (const float*)d_in[1];
    const float* w1       = (const float*)d_in[2];
    float* out    = (float*)d_out;
    float* logits = out + (size_t)MROWS * DF;

    char* ws    = (char*)d_ws;
    int*   sel  = (int*)(ws);                      // 8192 ints
    float* rwn  = (float*)(ws + 32768);            // 8192 floats
    int*   stok = (int*)(ws + 65536);              // 8192 ints
    float* srw  = (float*)(ws + 98304);            // 8192 floats
    int*   bexp = (int*)(ws + 131072);             // 64 ints
    __bf16* xb  = (__bf16*)(ws + (1 << 20));       // 4096x1024 bf16 = 8 MB
    __bf16* w1t = (__bf16*)(ws + (9 << 20));       // 16384x1024 bf16 = 32 MB

    router_kernel<<<NTOK / 4, 256, 0, stream>>>(x, router_w, logits, sel, rwn, xb);
    transpose_w<<<dim3(16, 256), 256, 0, stream>>>(w1, w1t);
    sort_kernel<<<1, 256, 0, stream>>>(sel, rwn, stok, srw, bexp);
    moe_gemm<<<dim3(16, NBLK), 256, 0, stream>>>(xb, w1t, stok, srw, bexp, out);
}

// Round 3
// 204.227 us; speedup vs baseline: 1.4439x; 1.0533x over previous
//
#include <hip/hip_runtime.h>
#include <hip/hip_bf16.h>
#include <cmath>

typedef float f32x4 __attribute__((ext_vector_type(4)));
typedef __bf16 bf16x8 __attribute__((ext_vector_type(8)));

#define NE 8
#define H 1024
#define DF 2048
#define WCOLS 16384
#define NTOK 4096
#define MROWS 8192
#define NBLK 64
#define TILE_E 4096          // elements per (128 x 32) bf16 tile

typedef const __attribute__((address_space(1))) unsigned int glb_u32;
typedef __attribute__((address_space(3))) unsigned int lds_u32;

__device__ __forceinline__ void async_load16(const void* g, void* l) {
    __builtin_amdgcn_global_load_lds((glb_u32*)g, (lds_u32*)l, 16, 0, 0);
}

// ------------- Router: logits + top-2 normalized weights --------------------
__global__ __launch_bounds__(256) void router_kernel(
    const float* __restrict__ x, const float* __restrict__ rw,
    float* __restrict__ logits, int* __restrict__ sel, float* __restrict__ rwn)
{
    int gid  = blockIdx.x * blockDim.x + threadIdx.x;
    int tok  = gid >> 6;
    int lane = gid & 63;
    const float* xr = x + (size_t)tok * H;
    float acc[NE];
#pragma unroll
    for (int e = 0; e < NE; ++e) acc[e] = 0.f;
#pragma unroll
    for (int it = 0; it < 4; ++it) {
        int k = (it * 64 + lane) * 4;
        float4 xv = *(const float4*)(xr + k);
#pragma unroll
        for (int e = 0; e < NE; ++e) {
            float4 wv = *(const float4*)(rw + e * H + k);
            acc[e] += xv.x * wv.x + xv.y * wv.y + xv.z * wv.z + xv.w * wv.w;
        }
    }
#pragma unroll
    for (int e = 0; e < NE; ++e) {
        float v = acc[e];
#pragma unroll
        for (int off = 32; off > 0; off >>= 1) v += __shfl_xor(v, off, 64);
        acc[e] = v;
    }
    if (lane == 0) {
#pragma unroll
        for (int e = 0; e < NE; ++e) logits[tok * NE + e] = acc[e];
        int i1 = 0; float m1 = acc[0];
#pragma unroll
        for (int e = 1; e < NE; ++e) if (acc[e] > m1) { m1 = acc[e]; i1 = e; }
        int i2 = -1; float m2 = -INFINITY;
#pragma unroll
        for (int e = 0; e < NE; ++e) if (e != i1 && acc[e] > m2) { m2 = acc[e]; i2 = e; }
        float e2 = expf(m2 - m1);
        float inv = 1.f / (1.f + e2);
        sel[tok * 2]     = i1;  sel[tok * 2 + 1] = i2;
        rwn[tok * 2]     = inv; rwn[tok * 2 + 1] = e2 * inv;
    }
}

// ------------- Stable counting sort by expert (1 block) ---------------------
__global__ __launch_bounds__(256) void sort_kernel(
    const int* __restrict__ sel, const float* __restrict__ rwn,
    int* __restrict__ stok, float* __restrict__ srw, int* __restrict__ bexp)
{
    __shared__ int cnt[NE][256];
    __shared__ int tot[NE];
    __shared__ int ebase[NE + 1];
    int t = threadIdx.x;
    int selv[32];
    int lc[NE];
#pragma unroll
    for (int e = 0; e < NE; ++e) lc[e] = 0;
    int base = t * 32;
    for (int j = 0; j < 32; ++j) { selv[j] = sel[base + j]; lc[selv[j]]++; }
#pragma unroll
    for (int e = 0; e < NE; ++e) cnt[e][t] = lc[e];
    __syncthreads();
    {   // parallel exclusive scan: expert g scanned by 32 threads (j = t&31)
        int g = t >> 5, j = t & 31;
        int s = 0, pre[8];
#pragma unroll
        for (int i = 0; i < 8; ++i) { pre[i] = s; s += cnt[g][j * 8 + i]; }
        int inc = s;
#pragma unroll
        for (int d = 1; d < 32; d <<= 1) {
            int v = __shfl_up(inc, d, 64);
            if (j >= d) inc += v;
        }
        int excl = inc - s;
#pragma unroll
        for (int i = 0; i < 8; ++i) cnt[g][j * 8 + i] = excl + pre[i];
        if (j == 31) tot[g] = inc;
    }
    __syncthreads();
    if (t == 0) {
        int s = 0;
        for (int e = 0; e < NE; ++e) { ebase[e] = s; s += tot[e]; }
        ebase[NE] = s;
    }
    __syncthreads();
    int off[NE];
#pragma unroll
    for (int e = 0; e < NE; ++e) off[e] = ebase[e] + cnt[e][t];
    for (int j = 0; j < 32; ++j) {
        int i = base + j;
        int e = selv[j];
        int pos = off[e]++;
        stok[pos] = i >> 1;
        srw[pos]  = rwn[i];
    }
    __syncthreads();
    if (t < NBLK) {
        int r = t * 128;
        int e = 0;
        while (e < NE - 1 && r >= ebase[e + 1]) ++e;
        bexp[t] = e;
    }
}

// ------------- Gather A into tiled layout At[64][32][128][32] bf16 ----------
__global__ __launch_bounds__(256) void gather_a(
    const float* __restrict__ x, const int* __restrict__ stok,
    __bf16* __restrict__ At)
{
    int b = blockIdx.x >> 2;           // m-block 0..63
    int q = blockIdx.x & 3;            // row quarter
    int tid = threadIdx.x;
    int lane = tid & 63, wv = tid >> 6;
    __bf16* base = At + (size_t)b * 32 * TILE_E;
#pragma unroll
    for (int r = 0; r < 8; ++r) {
        int m = q * 32 + wv * 8 + r;
        int tok = stok[b * 128 + m];
        const float* src = x + (size_t)tok * H;
#pragma unroll
        for (int h = 0; h < 2; ++h) {
            int k0 = h * 512 + lane * 8;
            float4 v0 = *(const float4*)(src + k0);
            float4 v1 = *(const float4*)(src + k0 + 4);
            bf16x8 p;
            p[0]=(__bf16)v0.x; p[1]=(__bf16)v0.y; p[2]=(__bf16)v0.z; p[3]=(__bf16)v0.w;
            p[4]=(__bf16)v1.x; p[5]=(__bf16)v1.y; p[6]=(__bf16)v1.z; p[7]=(__bf16)v1.w;
            int kb = k0 >> 5;
            int kc = k0 & 31;
            *(bf16x8*)(base + (size_t)kb * TILE_E + m * 32 + kc) = p;
        }
    }
}

// ------------- w1 -> tiled bf16 Wt[128][32][128][32] ------------------------
// Wt[c][kb][n][kc] = w1[kb*32+kc][c*128+n],  c = e*16+bx
__global__ __launch_bounds__(256) void transpose_w(
    const float* __restrict__ w1, __bf16* __restrict__ Wt)
{
    __shared__ float tile[32][132];
    int g  = blockIdx.x;               // 128 col-blocks x 32 kb = 4096
    int c  = g >> 5;
    int kb = g & 31;
    int tid = threadIdx.x;
    int kk = tid >> 3;                 // 0..31
    int cc = (tid & 7) * 16;           // 0..112
    const float* src = w1 + (size_t)(kb * 32 + kk) * WCOLS + c * 128 + cc;
#pragma unroll
    for (int i = 0; i < 4; ++i) {
        float4 v = *(const float4*)(src + i * 4);
        *(float4*)&tile[kk][cc + i * 4] = v;
    }
    __syncthreads();
    int n = tid >> 1, kc0 = (tid & 1) * 16;
    bf16x8 o0, o1;
#pragma unroll
    for (int i = 0; i < 8; ++i) {
        o0[i] = (__bf16)tile[kc0 + i][n];
        o1[i] = (__bf16)tile[kc0 + 8 + i][n];
    }
    __bf16* dst = Wt + (size_t)g * TILE_E + n * 32 + kc0;
    *(bf16x8*)dst       = o0;
    *(bf16x8*)(dst + 8) = o1;
}

// ------------- Block GEMM, double-buffered, tiled inputs --------------------
__global__ __launch_bounds__(256, 4) void moe_gemm(
    const __bf16* __restrict__ At, const __bf16* __restrict__ Wt,
    const float* __restrict__ srw, const int* __restrict__ bexp,
    float* __restrict__ out)
{
    __shared__ __align__(16) __bf16 As[2][128 * 32];
    __shared__ __align__(16) __bf16 Bs[2][128 * 32];
    __shared__ float rwS[128];

    int g  = blockIdx.x;
    int bx = g & 15;                   // n-tile
    int by = g >> 4;                   // m-block
    int tid = threadIdx.x;
    if (tid < 128) rwS[tid] = srw[by * 128 + tid];
    int e = bexp[by];

    int lane = tid & 63;
    int wv   = tid >> 6;

    const __bf16* aT = At + (size_t)by * 32 * TILE_E + wv * 1024 + lane * 8;
    const __bf16* bT = Wt + (size_t)(e * 16 + bx) * 32 * TILE_E + wv * 1024 + lane * 8;
    __bf16* aL0 = &As[0][wv * 1024];
    __bf16* aL1 = &As[1][wv * 1024];
    __bf16* bL0 = &Bs[0][wv * 1024];
    __bf16* bL1 = &Bs[1][wv * 1024];

    int wm   = (wv & 1) * 64;
    int wn   = (wv >> 1) * 64;
    int quad = lane >> 4;
    int l16  = lane & 15;
    int kf   = quad * 8;

    f32x4 acc[4][4];
#pragma unroll
    for (int i = 0; i < 4; ++i)
#pragma unroll
        for (int j = 0; j < 4; ++j) acc[i][j] = (f32x4){0.f, 0.f, 0.f, 0.f};

    // prologue: stage kb=0 into buffer 0
    async_load16(aT,       aL0);
    async_load16(aT + 512, aL0 + 512);
    async_load16(bT,       bL0);
    async_load16(bT + 512, bL0 + 512);

    for (int kb = 0; kb < 32; ++kb) {
        int cur = kb & 1;
        __syncthreads();               // drains vmcnt(0): current buffer ready
        if (kb < 31) {                 // stage kb+1 into other buffer (stays in flight)
            const __bf16* aN = aT + (size_t)(kb + 1) * TILE_E;
            const __bf16* bN = bT + (size_t)(kb + 1) * TILE_E;
            __bf16* aD = cur ? aL0 : aL1;
            __bf16* bD = cur ? bL0 : bL1;
            async_load16(aN,       aD);
            async_load16(aN + 512, aD + 512);
            async_load16(bN,       bD);
            async_load16(bN + 512, bD + 512);
        }
        bf16x8 af[4], bfr[4];
#pragma unroll
        for (int i = 0; i < 4; ++i)
            af[i] = *(const bf16x8*)&As[cur][(wm + i * 16 + l16) * 32 + kf];
#pragma unroll
        for (int j = 0; j < 4; ++j)
            bfr[j] = *(const bf16x8*)&Bs[cur][(wn + j * 16 + l16) * 32 + kf];
#pragma unroll
        for (int i = 0; i < 4; ++i)
#pragma unroll
            for (int j = 0; j < 4; ++j)
                acc[i][j] = __builtin_amdgcn_mfma_f32_16x16x32_bf16(
                    af[i], bfr[j], acc[i][j], 0, 0, 0);
        // barrier WITHOUT vm drain: fragments are in regs (lgkmcnt 0), the
        // in-flight next-stage loads survive the barrier.
        __builtin_amdgcn_s_waitcnt(0xC07F);   // lgkmcnt(0), vm/exp no-wait
        __builtin_amdgcn_s_barrier();
    }

    // epilogue: gelu (tanh form, |err|<3e-3) * rw
#pragma unroll
    for (int i = 0; i < 4; ++i) {
#pragma unroll
        for (int r = 0; r < 4; ++r) {
            int m = wm + i * 16 + quad * 4 + r;
            float rwv = rwS[m];
            size_t orow = (size_t)(by * 128 + m) * DF + bx * 128;
#pragma unroll
            for (int j = 0; j < 4; ++j) {
                float val = acc[i][j][r];
                float u = 0.7978845608028654f * val * (1.f + 0.044715f * val * val);
                float t = __expf(-2.f * fabsf(u));
                float th = (1.f - t) / (1.f + t);
                th = u < 0.f ? -th : th;
                float gv = 0.5f * val * (1.f + th);
                out[orow + wn + j * 16 + l16] = gv * rwv;
            }
        }
    }
}

extern "C" void kernel_launch(void* const* d_in, const int* in_sizes, int n_in,
                              void* d_out, int out_size, void* d_ws, size_t ws_size,
                              hipStream_t stream) {
    (void)in_sizes; (void)n_in; (void)out_size; (void)ws_size;
    const float* x        = (const float*)d_in[0];
    const float* router_w = (const float*)d_in[1];
    const float* w1       = (const float*)d_in[2];
    float* out    = (float*)d_out;
    float* logits = out + (size_t)MROWS * DF;

    char* ws    = (char*)d_ws;
    int*   sel  = (int*)(ws);
    float* rwn  = (float*)(ws + 0x8000);
    int*   stok = (int*)(ws + 0x10000);
    float* srw  = (float*)(ws + 0x18000);
    int*   bexp = (int*)(ws + 0x20000);
    __bf16* At  = (__bf16*)(ws + (1 << 20));              // 16 MB
    __bf16* Wt  = (__bf16*)(ws + (1 << 20) + (16 << 20)); // 32 MB

    router_kernel<<<NTOK / 4, 256, 0, stream>>>(x, router_w, logits, sel, rwn);
    transpose_w<<<4096, 256, 0, stream>>>(w1, Wt);
    sort_kernel<<<1, 256, 0, stream>>>(sel, rwn, stok, srw, bexp);
    gather_a<<<256, 256, 0, stream>>>(x, stok, At);
    moe_gemm<<<16 * NBLK, 256, 0, stream>>>(At, Wt, srw, bexp, out);
}

// Round 4
// 189.072 us; speedup vs baseline: 1.5596x; 1.0802x over previous
//
#include <hip/hip_runtime.h>
#include <hip/hip_bf16.h>
#include <cmath>

typedef float f32x16 __attribute__((ext_vector_type(16)));
typedef __bf16 bf16x8 __attribute__((ext_vector_type(8)));
typedef __bf16 bf16x4 __attribute__((ext_vector_type(4)));

#define NE 8
#define H 1024
#define DF 2048
#define WCOLS 16384
#define NTOK 4096
#define MROWS 8192
#define NBLK 64
#define TILE_E 4096          // elements per (128 x 32) bf16 tile

typedef const __attribute__((address_space(1))) unsigned int glb_u32;
typedef __attribute__((address_space(3))) unsigned int lds_u32;

__device__ __forceinline__ void async_load16(const void* g, void* l) {
    __builtin_amdgcn_global_load_lds((glb_u32*)g, (lds_u32*)l, 16, 0, 0);
}

// ---- prep: blocks [0,1024) = router (+ x->bf16), [1024,5120) = w1 transpose -
__global__ __launch_bounds__(256) void prep_kernel(
    const float* __restrict__ x, const float* __restrict__ rw,
    const float* __restrict__ w1,
    float* __restrict__ logits, int* __restrict__ sel, float* __restrict__ rwn,
    __bf16* __restrict__ xb, __bf16* __restrict__ Wt)
{
    __shared__ float tile[32][132];
    int b = blockIdx.x;
    int tid = threadIdx.x;
    if (b < 1024) {
        // ---------------- router: 1 token per wave ----------------
        int tok  = b * 4 + (tid >> 6);
        int lane = tid & 63;
        const float* xr = x + (size_t)tok * H;
        __bf16* xbr = xb + (size_t)tok * H;
        float acc[NE];
#pragma unroll
        for (int e = 0; e < NE; ++e) acc[e] = 0.f;
#pragma unroll
        for (int it = 0; it < 4; ++it) {
            int k = (it * 64 + lane) * 4;
            float4 xv = *(const float4*)(xr + k);
            bf16x4 xc;
            xc[0] = (__bf16)xv.x; xc[1] = (__bf16)xv.y;
            xc[2] = (__bf16)xv.z; xc[3] = (__bf16)xv.w;
            *(bf16x4*)(xbr + k) = xc;
#pragma unroll
            for (int e = 0; e < NE; ++e) {
                float4 wv = *(const float4*)(rw + e * H + k);
                acc[e] += xv.x * wv.x + xv.y * wv.y + xv.z * wv.z + xv.w * wv.w;
            }
        }
#pragma unroll
        for (int e = 0; e < NE; ++e) {
            float v = acc[e];
#pragma unroll
            for (int off = 32; off > 0; off >>= 1) v += __shfl_xor(v, off, 64);
            acc[e] = v;
        }
        if (lane == 0) {
#pragma unroll
            for (int e = 0; e < NE; ++e) logits[tok * NE + e] = acc[e];
            int i1 = 0; float m1 = acc[0];
#pragma unroll
            for (int e = 1; e < NE; ++e) if (acc[e] > m1) { m1 = acc[e]; i1 = e; }
            int i2 = -1; float m2 = -INFINITY;
#pragma unroll
            for (int e = 0; e < NE; ++e) if (e != i1 && acc[e] > m2) { m2 = acc[e]; i2 = e; }
            float e2 = expf(m2 - m1);
            float inv = 1.f / (1.f + e2);
            sel[tok * 2]     = i1;  sel[tok * 2 + 1] = i2;
            rwn[tok * 2]     = inv; rwn[tok * 2 + 1] = e2 * inv;
        }
        return;
    }
    // ---------------- transpose: Wt[c][kb][n][kc] = w1[kb*32+kc][c*128+n] ----
    int g  = b - 1024;                 // 0..4095
    int c  = g >> 5;
    int kb = g & 31;
    int kk = tid >> 3;                 // 0..31
    int cc = (tid & 7) * 16;           // 0..112
    const float* src = w1 + (size_t)(kb * 32 + kk) * WCOLS + c * 128 + cc;
#pragma unroll
    for (int i = 0; i < 4; ++i) {
        float4 v = *(const float4*)(src + i * 4);
        *(float4*)&tile[kk][cc + i * 4] = v;
    }
    __syncthreads();
    int n = tid >> 1, kc0 = (tid & 1) * 16;
    bf16x8 o0, o1;
#pragma unroll
    for (int i = 0; i < 8; ++i) {
        o0[i] = (__bf16)tile[kc0 + i][n];
        o1[i] = (__bf16)tile[kc0 + 8 + i][n];
    }
    __bf16* dst = Wt + (size_t)g * TILE_E + n * 32 + kc0;
    *(bf16x8*)dst       = o0;
    *(bf16x8*)(dst + 8) = o1;
}

// ------------- Stable counting sort by expert (1 block x 1024) --------------
__global__ __launch_bounds__(1024) void sort_kernel(
    const int* __restrict__ sel, const float* __restrict__ rwn,
    int* __restrict__ stok, float* __restrict__ srw, int* __restrict__ bexp)
{
    __shared__ int cnt[NE][1024];
    __shared__ int wtot[NE][2];
    __shared__ int ebase[NE + 1];
    int t = threadIdx.x;
    int selv[8];
    int lc[NE];
#pragma unroll
    for (int e = 0; e < NE; ++e) lc[e] = 0;
    int base = t * 8;
#pragma unroll
    for (int j = 0; j < 8; ++j) { selv[j] = sel[base + j]; lc[selv[j]]++; }
#pragma unroll
    for (int e = 0; e < NE; ++e) cnt[e][t] = lc[e];
    __syncthreads();
    // scan: expert g scanned by 128 threads (2 waves)
    int g = t >> 7, j = t & 127, jl = j & 63;
    int s = 0, pre[8];
#pragma unroll
    for (int i = 0; i < 8; ++i) { pre[i] = s; s += cnt[g][j * 8 + i]; }
    int inc = s;
#pragma unroll
    for (int d = 1; d < 64; d <<= 1) {
        int v = __shfl_up(inc, d, 64);
        if (jl >= d) inc += v;
    }
    if (jl == 63) wtot[g][j >> 6] = inc;
    __syncthreads();
    int add = (j >= 64) ? wtot[g][0] : 0;
    int excl = inc - s + add;
#pragma unroll
    for (int i = 0; i < 8; ++i) cnt[g][j * 8 + i] = excl + pre[i];
    __syncthreads();
    if (t == 0) {
        int acc = 0;
        for (int e = 0; e < NE; ++e) { ebase[e] = acc; acc += wtot[e][0] + wtot[e][1]; }
        ebase[NE] = acc;
    }
    __syncthreads();
    int off[NE];
#pragma unroll
    for (int e = 0; e < NE; ++e) off[e] = ebase[e] + cnt[e][t];
#pragma unroll
    for (int j2 = 0; j2 < 8; ++j2) {
        int i = base + j2;
        int e = selv[j2];
        int pos = off[e]++;
        stok[pos] = i >> 1;
        srw[pos]  = rwn[i];
    }
    __syncthreads();
    if (t < NBLK) {
        int r = t * 128;
        int e = 0;
        while (e < NE - 1 && r >= ebase[e + 1]) ++e;
        bexp[t] = e;
    }
}

// ------------- Block GEMM: fused A-gather, dbuf, 32x32x16 MFMA --------------
__global__ __launch_bounds__(256, 4) void moe_gemm(
    const __bf16* __restrict__ xb, const __bf16* __restrict__ Wt,
    const int* __restrict__ stok, const float* __restrict__ srw,
    const int* __restrict__ bexp, float* __restrict__ out)
{
    __shared__ __align__(16) __bf16 As[2][4096];
    __shared__ __align__(16) __bf16 Bs[2][4096];
    __shared__ int   tokS[128];
    __shared__ float rwS[128];

    int g = blockIdx.x;
    // XCD swizzle: xcd = g&7; all 16 bx of 8 consecutive by share an XCD
    int by = (g & 7) * 8 + ((g >> 3) & 7);
    int bx = g >> 6;
    int tid = threadIdx.x;
    if (tid < 128) {
        tokS[tid] = stok[by * 128 + tid];
        rwS[tid]  = srw[by * 128 + tid];
    }
    int e = bexp[by];
    __syncthreads();

    int lane = tid & 63;
    int wv   = tid >> 6;
    int rsub = lane >> 2;              // 0..15
    int kcE  = (lane & 3) * 8;         // bf16 elems (16B chunk)
    int r0   = wv * 32 + rsub;
    int r1   = r0 + 16;

    const __bf16* aS0 = xb + (size_t)tokS[r0] * H + kcE;   // gathered rows
    const __bf16* aS1 = xb + (size_t)tokS[r1] * H + kcE;
    const __bf16* bT  = Wt + (size_t)(e * 16 + bx) * 32 * TILE_E + wv * 1024 + lane * 8;
    __bf16* aL[2] = { &As[0][wv * 1024], &As[1][wv * 1024] };
    __bf16* bL[2] = { &Bs[0][wv * 1024], &Bs[1][wv * 1024] };

    int wm  = (wv & 1) * 64;
    int wn  = (wv >> 1) * 64;
    int l32 = lane & 31;
    int khi = (lane >> 5) * 8;         // k offset within 16-k half

    f32x16 acc[2][2];
#pragma unroll
    for (int i = 0; i < 2; ++i)
#pragma unroll
        for (int j = 0; j < 2; ++j)
#pragma unroll
            for (int r = 0; r < 16; ++r) acc[i][j][r] = 0.f;

    // prologue: stage kb=0 into buffer 0
    async_load16(aS0, aL[0]);
    async_load16(aS1, aL[0] + 512);
    async_load16(bT,  bL[0]);
    async_load16(bT + 512, bL[0] + 512);

    for (int kb = 0; kb < 32; ++kb) {
        int cur = kb & 1;
        __syncthreads();               // drains vmcnt: buffer cur ready; also
                                       // (per-wave lgkm drain) orders LDS reuse
        if (kb < 31) {
            const __bf16* aN0 = aS0 + (kb + 1) * 32;
            const __bf16* aN1 = aS1 + (kb + 1) * 32;
            const __bf16* bN  = bT + (size_t)(kb + 1) * TILE_E;
            async_load16(aN0, aL[1 - cur]);
            async_load16(aN1, aL[1 - cur] + 512);
            async_load16(bN,  bL[1 - cur]);
            async_load16(bN + 512, bL[1 - cur] + 512);
        }
        bf16x8 af[2][2], bfr[2][2];
#pragma unroll
        for (int h = 0; h < 2; ++h) {
#pragma unroll
            for (int ti = 0; ti < 2; ++ti)
                af[ti][h] = *(const bf16x8*)&As[cur][(wm + ti * 32 + l32) * 32 + h * 16 + khi];
#pragma unroll
            for (int tj = 0; tj < 2; ++tj)
                bfr[tj][h] = *(const bf16x8*)&Bs[cur][(wn + tj * 32 + l32) * 32 + h * 16 + khi];
        }
#pragma unroll
        for (int h = 0; h < 2; ++h)
#pragma unroll
            for (int ti = 0; ti < 2; ++ti)
#pragma unroll
                for (int tj = 0; tj < 2; ++tj)
                    acc[ti][tj] = __builtin_amdgcn_mfma_f32_32x32x16_bf16(
                        af[ti][h], bfr[tj][h], acc[ti][tj], 0, 0, 0);
    }

    // epilogue: gelu (tanh form) * rw; C/D: row=(reg&3)+8*(reg>>2)+4*(lane>>5)
    int rowh = (lane >> 5) * 4;
#pragma unroll
    for (int ti = 0; ti < 2; ++ti)
#pragma unroll
        for (int tj = 0; tj < 2; ++tj)
#pragma unroll
            for (int reg = 0; reg < 16; ++reg) {
                int row = (reg & 3) + 8 * (reg >> 2) + rowh;
                int m = wm + ti * 32 + row;
                int n = wn + tj * 32 + l32;
                float val = acc[ti][tj][reg];
                float u = 0.7978845608028654f * val * (1.f + 0.044715f * val * val);
                float t = __expf(-2.f * fabsf(u));
                float th = (1.f - t) / (1.f + t);
                th = u < 0.f ? -th : th;
                float gv = 0.5f * val * (1.f + th) * rwS[m];
                out[(size_t)(by * 128 + m) * DF + bx * 128 + n] = gv;
            }
}

extern "C" void kernel_launch(void* const* d_in, const int* in_sizes, int n_in,
                              void* d_out, int out_size, void* d_ws, size_t ws_size,
                              hipStream_t stream) {
    (void)in_sizes; (void)n_in; (void)out_size; (void)ws_size;
    const float* x        = (const float*)d_in[0];
    const float* router_w = (const float*)d_in[1];
    const float* w1       = (const float*)d_in[2];
    float* out    = (float*)d_out;
    float* logits = out + (size_t)MROWS * DF;

    char* ws    = (char*)d_ws;
    int*   sel  = (int*)(ws);
    float* rwn  = (float*)(ws + 0x8000);
    int*   stok = (int*)(ws + 0x10000);
    float* srw  = (float*)(ws + 0x18000);
    int*   bexp = (int*)(ws + 0x20000);
    __bf16* xb  = (__bf16*)(ws + (1 << 20));             // 8 MB
    __bf16* Wt  = (__bf16*)(ws + (1 << 20) + (8 << 20)); // 32 MB

    prep_kernel<<<5120, 256, 0, stream>>>(x, router_w, w1, logits, sel, rwn, xb, Wt);
    sort_kernel<<<1, 1024, 0, stream>>>(sel, rwn, stok, srw, bexp);
    moe_gemm<<<16 * NBLK, 256, 0, stream>>>(xb, Wt, stok, srw, bexp, out);
}